// Round 17
// baseline (107.729 us; speedup 1.0000x reference)
//
#include <hip/hip_runtime.h>
#include <hip/hip_bf16.h>

// Problem constants
#define NB 16384      // batch rows
#define DD 512        // IN+OUT
#define NCOLS 4096    // 4*OUT*NCELL

typedef __attribute__((ext_vector_type(8))) short short8;
typedef __attribute__((ext_vector_type(4))) float f32x4;

// Fast-approx activations (R15-proven: output tol 0.0837 >> 1-ulp rcp/exp2 err)
__device__ __forceinline__ float sigmoidf_(float x) {
    float e = __builtin_amdgcn_exp2f(-1.442695041f * x);   // exp(-x)
    return __builtin_amdgcn_rcpf(1.f + e);
}
__device__ __forceinline__ float tanhf_(float x) {
    float e = __builtin_amdgcn_exp2f(-2.885390082f * x);   // exp(-2x)
    return 2.f * __builtin_amdgcn_rcpf(1.f + e) - 1.f;
}

#define GLOAD_LDS16(g, l) __builtin_amdgcn_global_load_lds( \
    (__attribute__((address_space(1))) void*)(g), \
    (__attribute__((address_space(3))) void*)(l), 16, 0, 0)

// ---------------- P1 (fused): feats->bf16 + ctrl gates | W_gates repack ----------
// blocks 0..4095: prep (wave-per-row).  blocks 4096..5119: repack to W3.
// W3 row index: cell*1024 + ob*128 + oh*64 + gate*16 + oi  (o = ob*32+oh*16+oi)
__global__ void k_pre(const float* __restrict__ x, const float* __restrict__ h,
                      const float* __restrict__ Wc, const float* __restrict__ bc,
                      const float* __restrict__ Wg,
                      __hip_bfloat16* __restrict__ featsB, float* __restrict__ gates,
                      __hip_bfloat16* __restrict__ W3, int* __restrict__ counts) {
    int bid = blockIdx.x;
    if (bid == 0 && threadIdx.x < 6) counts[threadIdx.x] = 0;  // replaces memset node
    if (bid < 4096) {
        int wave = bid * 4 + (threadIdx.x >> 6);  // == row
        int lane = threadIdx.x & 63;
        int row = wave;
        int k0 = lane * 8;
        const float* src = (k0 < 256) ? (x + (size_t)row * 256 + k0)
                                      : (h + (size_t)row * 256 + k0 - 256);
        float4 f0 = ((const float4*)src)[0];
        float4 f1 = ((const float4*)src)[1];
        float fv[8] = {f0.x, f0.y, f0.z, f0.w, f1.x, f1.y, f1.z, f1.w};
        __hip_bfloat16 tmp[8];
#pragma unroll
        for (int j = 0; j < 8; ++j) tmp[j] = __float2bfloat16(fv[j]);
        *reinterpret_cast<short8*>(featsB + (size_t)row * 512 + k0) =
            *reinterpret_cast<short8*>(tmp);
        float acc[4] = {0.f, 0.f, 0.f, 0.f};
#pragma unroll
        for (int j = 0; j < 8; ++j) {
            float4 w = ((const float4*)Wc)[k0 + j];
            acc[0] += fv[j] * w.x; acc[1] += fv[j] * w.y;
            acc[2] += fv[j] * w.z; acc[3] += fv[j] * w.w;
        }
#pragma unroll
        for (int off = 32; off; off >>= 1) {
#pragma unroll
            for (int c = 0; c < 4; ++c) acc[c] += __shfl_xor(acc[c], off);
        }
        if (lane == 0) {
            float l[4];
#pragma unroll
            for (int c = 0; c < 4; ++c) l[c] = acc[c] + bc[c];
            int i1 = 0;
#pragma unroll
            for (int c = 1; c < 4; ++c) if (l[c] > l[i1]) i1 = c;  // ties -> lowest
            int i2 = -1;
#pragma unroll
            for (int c = 0; c < 4; ++c)
                if (c != i1 && (i2 < 0 || l[c] > l[i2])) i2 = c;
            // selection must match numpy: f32 logits, exact expf (once per row)
            float e = __expf(l[i2] - l[i1]);   // <= 1
            float p1 = 1.f / (1.f + e);
            float p2 = e / (1.f + e);
            float g[4] = {0.f, 0.f, 0.f, 0.f};
            g[i1] = p1; g[i2] = p2;
            float4 gv; gv.x = g[0]; gv.y = g[1]; gv.z = g[2]; gv.w = g[3];
            *(float4*)(gates + (size_t)row * 4) = gv;
        }
    } else {
        int t = (bid - 4096) * 256 + threadIdx.x;
        int k0 = (t >> 12) * 8;
        int col = t & 4095;
        int cell = col >> 10, gate = (col >> 8) & 3, o = col & 255;
        int ob = o >> 5, oh = (o >> 4) & 1, oi = o & 15;
        int w3row = cell * 1024 + ob * 128 + oh * 64 + gate * 16 + oi;
        __hip_bfloat16 tmp[8];
#pragma unroll
        for (int j = 0; j < 8; ++j)
            tmp[j] = __float2bfloat16(Wg[(size_t)(k0 + j) * 4096 + col]);
        *reinterpret_cast<short8*>(W3 + (size_t)w3row * 512 + k0) =
            *reinterpret_cast<short8*>(tmp);
    }
}

// ---------------- P2: bucket rows by active cell-pair (wave-aggregated atomics) ----
__global__ void k_bucket(const float* __restrict__ gates, int* __restrict__ counts,
                         int* __restrict__ rowList) {
    int row = blockIdx.x * 256 + threadIdx.x;
    int lane = threadIdx.x & 63;
    float4 g = *(const float4*)(gates + (size_t)row * 4);
    int i1 = 0; float m1 = g.x;
    if (g.y > m1) { m1 = g.y; i1 = 1; }
    if (g.z > m1) { m1 = g.z; i1 = 2; }
    if (g.w > m1) { m1 = g.w; i1 = 3; }
    int i2 = -1; float m2 = -1.f;
    if (i1 != 0)             { m2 = g.x; i2 = 0; }
    if (i1 != 1 && g.y > m2) { m2 = g.y; i2 = 1; }
    if (i1 != 2 && g.z > m2) { m2 = g.z; i2 = 2; }
    if (i1 != 3 && g.w > m2) { m2 = g.w; i2 = 3; }
    int a = min(i1, i2), b = max(i1, i2);
    int pid = (a == 0) ? (b - 1) : (a == 1) ? (1 + b) : 5;
#pragma unroll
    for (int q = 0; q < 6; ++q) {
        unsigned long long m = __ballot(pid == q);   // uniform execution
        if (pid == q) {
            int leader = __ffsll((long long)m) - 1;
            int base = 0;
            if (lane == leader) base = atomicAdd(counts + q, __popcll(m));
            base = __shfl(base, leader);
            int prefix = __popcll(m & ((1ull << lane) - 1ull));
            rowList[q * 16384 + base + prefix] = row;
        }
    }
}

// ---------------- Main: R7-proven 128-row K-loop + optimized parallel epilogue ---
// Block: 512 thr / 8 waves, 128 gathered rows x 256 cols (2 cells) for one ob.
// B through LDS (shared across wr -> per-FLOP L2/L3 traffic halved vs 64-row
// reg-B design: 668 -> ~400 MB). K-loop/sync byte-identical to R7 (passed 2x).
// Epilogue: cin/gates prefetched to LDS (R14), fast activations (R15), and
// compute-PARALLEL phases: ch1 waves store partials, one barrier, ch0 waves
// compute concurrently then add+write out directly (A+B order preserved).
__launch_bounds__(512, 4)
__global__ void k_main(const __hip_bfloat16* __restrict__ featsB,
                       const __hip_bfloat16* __restrict__ W3,
                       const float* __restrict__ cin,
                       const float* __restrict__ gates,
                       const float* __restrict__ bg,
                       const int* __restrict__ counts,
                       const int* __restrict__ rowList,
                       float* __restrict__ out) {
    __shared__ char smem[49152];          // As 16K | Bs 32K ; oAcc 32K aliases
    __shared__ float cinS[4096];          // [128][32] = 16 KB
    __shared__ float gatesS[512];         // [128][4]  = 2 KB
    __shared__ int rlist[128];
    char* As = smem;
    char* Bs = smem + 16384;
    float* oAcc = (float*)smem;           // [2][128][32] f32 (epilogue partials)

    int tid = threadIdx.x;
    int wave = tid >> 6, lane = tid & 63;
    int wr = wave >> 2, wc = wave & 3;
    int hi = lane >> 4, lsw = lane & 7, l15 = lane & 15;

    // XCD-clustered decode (R7): lin%8 = XCD = bq%8
    int lin = blockIdx.x;                 // [0, 1088)
    int r_ = lin & 7;
    int v_ = lin >> 3;                    // [0, 136)
    int ob = v_ & 7;
    int bq = r_ + ((v_ >> 3) << 3);       // [0, 136), bq%8 == r_

    int c0_ = counts[0], c1_ = counts[1], c2_ = counts[2],
        c3_ = counts[3], c4_ = counts[4], c5_ = counts[5];
    int s1 = (c0_ + 127) >> 7;
    int s2 = s1 + ((c1_ + 127) >> 7);
    int s3 = s2 + ((c2_ + 127) >> 7);
    int s4 = s3 + ((c3_ + 127) >> 7);
    int s5 = s4 + ((c4_ + 127) >> 7);
    int total = s5 + ((c5_ + 127) >> 7);
    if (bq >= total) return;
    int p, chunk, cnt, cA, cB;
    if      (bq < s1) { p = 0; chunk = bq;      cnt = c0_; cA = 0; cB = 1; }
    else if (bq < s2) { p = 1; chunk = bq - s1; cnt = c1_; cA = 0; cB = 2; }
    else if (bq < s3) { p = 2; chunk = bq - s2; cnt = c2_; cA = 0; cB = 3; }
    else if (bq < s4) { p = 3; chunk = bq - s3; cnt = c3_; cA = 1; cB = 2; }
    else if (bq < s5) { p = 4; chunk = bq - s4; cnt = c4_; cA = 1; cB = 3; }
    else              { p = 5; chunk = bq - s5; cnt = c5_; cA = 2; cB = 3; }
    int nvalid = min(128, cnt - chunk * 128);
    int rowbase = p * 16384 + chunk * 128;

    if (tid < 128) rlist[tid] = (tid < nvalid) ? rowList[rowbase + tid] : 0;
    __syncthreads();

    // A gather descriptors (R7-proven): 128-B rows = 8 chunks; swizzle key = row&7
    int e0 = tid,        rA0 = e0 >> 3, gA0 = (e0 & 7) ^ (rA0 & 7);
    int e1 = 512 + tid,  rA1 = e1 >> 3, gA1 = (e1 & 7) ^ (rA1 & 7);
    const __hip_bfloat16* sA0 = featsB + (size_t)rlist[rA0] * 512 + gA0 * 8;
    const __hip_bfloat16* sA1 = featsB + (size_t)rlist[rA1] * 512 + gA1 * 8;
    int dA0 = e0 * 16, dA1 = e1 * 16;

    // B descriptors (R7-proven)
    int f0_ = tid,         rB0 = f0_ >> 3, gB0 = (f0_ & 7) ^ (rB0 & 7);
    int f1_ = 512 + tid,   rB1 = f1_ >> 3, gB1 = (f1_ & 7) ^ (rB1 & 7);
    int f2_ = 1024 + tid,  rB2 = f2_ >> 3, gB2 = (f2_ & 7) ^ (rB2 & 7);
    int f3_ = 1536 + tid,  rB3 = f3_ >> 3, gB3 = (f3_ & 7) ^ (rB3 & 7);
    const __hip_bfloat16* sB0 = W3 + (size_t)(cA * 1024 + ob * 128 + rB0) * 512 + gB0 * 8;
    const __hip_bfloat16* sB1 = W3 + (size_t)(cA * 1024 + ob * 128 + rB1) * 512 + gB1 * 8;
    const __hip_bfloat16* sB2 = W3 + (size_t)(cB * 1024 + ob * 128 + (rB2 & 127)) * 512 + gB2 * 8;
    const __hip_bfloat16* sB3 = W3 + (size_t)(cB * 1024 + ob * 128 + (rB3 & 127)) * 512 + gB3 * 8;
    int dB0 = f0_ * 16, dB1 = f1_ * 16, dB2 = f2_ * 16, dB3 = f3_ * 16;

    // epilogue-operand prefetch (R14): cinS 1024 chunks (2/thread), gatesS 128
    {
        int ec0 = tid,       rc0 = ec0 >> 3, qc0 = ec0 & 7;
        int ec1 = 512 + tid, rc1 = ec1 >> 3, qc1 = ec1 & 7;
        GLOAD_LDS16(cin + (size_t)rlist[rc0] * 256 + ob * 32 + qc0 * 4,
                    (char*)cinS + ec0 * 16);
        GLOAD_LDS16(cin + (size_t)rlist[rc1] * 256 + ob * 32 + qc1 * 4,
                    (char*)cinS + ec1 * 16);
        if (tid < 128)
            GLOAD_LDS16(gates + (size_t)rlist[tid] * 4, (char*)gatesS + tid * 16);
    }

    f32x4 acc[4][4];
#pragma unroll
    for (int m = 0; m < 4; ++m)
#pragma unroll
        for (int n = 0; n < 4; ++n)
            acc[m][n] = (f32x4){0.f, 0.f, 0.f, 0.f};

    for (int kt = 0; kt < 8; ++kt) {
        int ko = kt * 64;
        GLOAD_LDS16(sA0 + ko, As + dA0);
        GLOAD_LDS16(sA1 + ko, As + dA1);
        GLOAD_LDS16(sB0 + ko, Bs + dB0);
        GLOAD_LDS16(sB1 + ko, Bs + dB1);
        GLOAD_LDS16(sB2 + ko, Bs + dB2);
        GLOAD_LDS16(sB3 + ko, Bs + dB3);
        __syncthreads();   // drains vmcnt + barrier
#pragma unroll
        for (int kk = 0; kk < 2; ++kk) {
            short8 fa[4], fb[4];
#pragma unroll
            for (int m = 0; m < 4; ++m) {
                int row = wr * 64 + m * 16 + l15;
                int chunkc = (kk * 4 + hi) ^ lsw;
                fa[m] = *reinterpret_cast<const short8*>(As + row * 128 + chunkc * 16);
            }
#pragma unroll
            for (int n = 0; n < 4; ++n) {
                int c2 = wc * 64 + n * 16 + l15;   // = ch*128 + ohh*64 + gate*16 + oi
                int chunkc = (kk * 4 + hi) ^ lsw;
                fb[n] = *reinterpret_cast<const short8*>(Bs + c2 * 128 + chunkc * 16);
            }
#pragma unroll
            for (int m = 0; m < 4; ++m)
#pragma unroll
                for (int n = 0; n < 4; ++n)
                    acc[m][n] = __builtin_amdgcn_mfma_f32_16x16x32_bf16(
                        fa[m], fb[n], acc[m][n], 0, 0, 0);
        }
        __syncthreads();
    }

    // ---- epilogue: parallel-compute two-phase pair reduce ----
    int ohh = wc & 1;
    int ch  = wc >> 1;
    int cell = ch ? cB : cA;
    int og = ob * 32 + ohh * 16 + l15;    // global o in [0,256)
    float bb0 = bg[cell * 1024 + 0 * 256 + og];
    float bb1 = bg[cell * 1024 + 1 * 256 + og];
    float bb2 = bg[cell * 1024 + 2 * 256 + og];
    float bb3 = bg[cell * 1024 + 3 * 256 + og];

    if (ch == 1) {    // cell-B waves: store partials to oAcc (aliases As/Bs —
                      // safe: last K-tile __syncthreads fenced all LDS reads)
#pragma unroll
        for (int m = 0; m < 4; ++m) {
#pragma unroll
            for (int reg = 0; reg < 4; ++reg) {
                int r = wr * 64 + m * 16 + hi * 4 + reg;
                float gw = gatesS[r * 4 + cell];
                float iv = sigmoidf_(acc[m][0][reg] + bb0);
                float jv = acc[m][1][reg] + bb1;
                float fv = sigmoidf_(acc[m][2][reg] + bb2);
                float ov = sigmoidf_(acc[m][3][reg] + bb3);
                float cv = cinS[r * 32 + ohh * 16 + l15];
                float ncl = fv * cv + iv * tanhf_(jv);
                float nhl = ov * tanhf_(ncl);
                oAcc[r * 32 + ohh * 16 + l15] = gw * nhl;
                oAcc[4096 + r * 32 + ohh * 16 + l15] = gw * ncl;
            }
        }
    }
    __syncthreads();
    if (ch == 0) {    // cell-A waves: compute own (overlapped with ch1 phase
                      // above), add partner partial, write out directly
#pragma unroll
        for (int m = 0; m < 4; ++m) {
#pragma unroll
            for (int reg = 0; reg < 4; ++reg) {
                int r = wr * 64 + m * 16 + hi * 4 + reg;
                float gw = gatesS[r * 4 + cell];
                float iv = sigmoidf_(acc[m][0][reg] + bb0);
                float jv = acc[m][1][reg] + bb1;
                float fv = sigmoidf_(acc[m][2][reg] + bb2);
                float ov = sigmoidf_(acc[m][3][reg] + bb3);
                float cv = cinS[r * 32 + ohh * 16 + l15];
                float ncl = fv * cv + iv * tanhf_(jv);
                float nhl = ov * tanhf_(ncl);
                // A + B order == previous rounds' (oAcc=A; oAcc+=B) bitwise
                float vnh = gw * nhl + oAcc[r * 32 + ohh * 16 + l15];
                float vnc = gw * ncl + oAcc[4096 + r * 32 + ohh * 16 + l15];
                if (r < nvalid) {
                    int grow = rlist[r];
                    out[(size_t)grow * 256 + og] = vnh;
                    out[(size_t)NB * 256 + (size_t)grow * 256 + og] = vnc;
                }
            }
        }
    }
}

extern "C" void kernel_launch(void* const* d_in, const int* in_sizes, int n_in,
                              void* d_out, int out_size, void* d_ws, size_t ws_size,
                              hipStream_t stream) {
    const float* x  = (const float*)d_in[0];
    const float* c  = (const float*)d_in[1];
    const float* h  = (const float*)d_in[2];
    const float* Wg = (const float*)d_in[3];
    const float* bg = (const float*)d_in[4];
    const float* Wc = (const float*)d_in[5];
    const float* bc = (const float*)d_in[6];
    float* out = (float*)d_out;

    const size_t featsB_bytes = (size_t)NB * DD * 2;        // 16.78 MB
    const size_t w3_bytes     = (size_t)NCOLS * DD * 2;     // 4.19 MB
    const size_t gates_bytes  = (size_t)NB * 4 * 4;         // 0.26 MB
    const size_t counts_bytes = 256;
    const size_t rlist_bytes  = (size_t)6 * 16384 * 4;      // 0.39 MB
    if (ws_size < featsB_bytes + w3_bytes + gates_bytes + counts_bytes + rlist_bytes)
        return;

    char* ws = (char*)d_ws;
    __hip_bfloat16* featsB = (__hip_bfloat16*)ws;
    __hip_bfloat16* W3     = (__hip_bfloat16*)(ws + featsB_bytes);
    float*          gatesW = (float*)(ws + featsB_bytes + w3_bytes);
    int*            counts = (int*)(ws + featsB_bytes + w3_bytes + gates_bytes);
    int*            rowLst = (int*)(ws + featsB_bytes + w3_bytes + gates_bytes + counts_bytes);

    k_pre<<<dim3(5120), dim3(256), 0, stream>>>(x, h, Wc, bc, Wg, featsB, gatesW,
                                                W3, counts);
    k_bucket<<<dim3(64), dim3(256), 0, stream>>>(gatesW, counts, rowLst);
    // 1088 = 8 XCD-residues x 17 chunk-groups x 8 obs; blocks with bq>=total exit
    k_main<<<dim3(1088), dim3(512), 0, stream>>>(featsB, W3, c, gatesW, bg,
                                                 counts, rowLst, out);
}

// Round 18
// 104.279 us; speedup vs baseline: 1.0331x; 1.0331x over previous
//
#include <hip/hip_runtime.h>
#include <hip/hip_bf16.h>

// Problem constants
#define NB 16384      // batch rows
#define DD 512        // IN+OUT
#define NCOLS 4096    // 4*OUT*NCELL

typedef __attribute__((ext_vector_type(8))) short short8;
typedef __attribute__((ext_vector_type(4))) float f32x4;

// Fast-approx activations (R15-proven: output tol 0.0837 >> 1-ulp rcp/exp2 err)
__device__ __forceinline__ float sigmoidf_(float x) {
    float e = __builtin_amdgcn_exp2f(-1.442695041f * x);   // exp(-x)
    return __builtin_amdgcn_rcpf(1.f + e);
}
__device__ __forceinline__ float tanhf_(float x) {
    float e = __builtin_amdgcn_exp2f(-2.885390082f * x);   // exp(-2x)
    return 2.f * __builtin_amdgcn_rcpf(1.f + e) - 1.f;
}

#define GLOAD_LDS16(g, l) __builtin_amdgcn_global_load_lds( \
    (__attribute__((address_space(1))) void*)(g), \
    (__attribute__((address_space(3))) void*)(l), 16, 0, 0)

// ---------------- P1 (fused): feats->bf16 + ctrl gates | W_gates repack to W4 ----
// W4 layout (R8-proven): chunk c = (((cell*8+ob)*8 + rowg)*16 + kkg)*64 + lane,
// rowg = oh*4 + gate; chunk holds k = kkg*32 + (lane>>4)*8 .. +8 of column
// (cell,gate,ob,oh,oi=lane&15). A wave's B-fragment load in k_main is then
// uniform_base + lane*16 -> one fully-coalesced 1KB wave load.
__global__ void k_pre(const float* __restrict__ x, const float* __restrict__ h,
                      const float* __restrict__ Wc, const float* __restrict__ bc,
                      const float* __restrict__ Wg,
                      __hip_bfloat16* __restrict__ featsB, float* __restrict__ gates,
                      __hip_bfloat16* __restrict__ W4) {
    int bid = blockIdx.x;
    if (bid < 4096) {
        int wave = bid * 4 + (threadIdx.x >> 6);  // == row
        int lane = threadIdx.x & 63;
        int row = wave;
        int k0 = lane * 8;
        const float* src = (k0 < 256) ? (x + (size_t)row * 256 + k0)
                                      : (h + (size_t)row * 256 + k0 - 256);
        float4 f0 = ((const float4*)src)[0];
        float4 f1 = ((const float4*)src)[1];
        float fv[8] = {f0.x, f0.y, f0.z, f0.w, f1.x, f1.y, f1.z, f1.w};
        __hip_bfloat16 tmp[8];
#pragma unroll
        for (int j = 0; j < 8; ++j) tmp[j] = __float2bfloat16(fv[j]);
        *reinterpret_cast<short8*>(featsB + (size_t)row * 512 + k0) =
            *reinterpret_cast<short8*>(tmp);
        float acc[4] = {0.f, 0.f, 0.f, 0.f};
#pragma unroll
        for (int j = 0; j < 8; ++j) {
            float4 w = ((const float4*)Wc)[k0 + j];
            acc[0] += fv[j] * w.x; acc[1] += fv[j] * w.y;
            acc[2] += fv[j] * w.z; acc[3] += fv[j] * w.w;
        }
#pragma unroll
        for (int off = 32; off; off >>= 1) {
#pragma unroll
            for (int c = 0; c < 4; ++c) acc[c] += __shfl_xor(acc[c], off);
        }
        if (lane == 0) {
            float l[4];
#pragma unroll
            for (int c = 0; c < 4; ++c) l[c] = acc[c] + bc[c];
            int i1 = 0;
#pragma unroll
            for (int c = 1; c < 4; ++c) if (l[c] > l[i1]) i1 = c;  // ties -> lowest
            int i2 = -1;
#pragma unroll
            for (int c = 0; c < 4; ++c)
                if (c != i1 && (i2 < 0 || l[c] > l[i2])) i2 = c;
            // selection must match numpy: f32 logits, exact expf here (cheap, once)
            float e = __expf(l[i2] - l[i1]);   // <= 1
            float p1 = 1.f / (1.f + e);
            float p2 = e / (1.f + e);
            float g[4] = {0.f, 0.f, 0.f, 0.f};
            g[i1] = p1; g[i2] = p2;
            float4 gv; gv.x = g[0]; gv.y = g[1]; gv.z = g[2]; gv.w = g[3];
            *(float4*)(gates + (size_t)row * 4) = gv;
        }
    } else {
        int c = (bid - 4096) * 256 + threadIdx.x;   // chunk id, 0..262143
        int lane = c & 63;
        int kkg  = (c >> 6) & 15;
        int rowg = (c >> 10) & 7;
        int ob   = (c >> 13) & 7;
        int cell = c >> 16;
        int oi = lane & 15, hi = lane >> 4;
        int gate = rowg & 3, oh = rowg >> 2;
        int col = cell * 1024 + gate * 256 + ob * 32 + oh * 16 + oi;
        int kb = kkg * 32 + hi * 8;
        __hip_bfloat16 tmp[8];
#pragma unroll
        for (int j = 0; j < 8; ++j)
            tmp[j] = __float2bfloat16(Wg[(size_t)(kb + j) * 4096 + col]);
        *reinterpret_cast<short8*>(W4 + (size_t)c * 8) = *reinterpret_cast<short8*>(tmp);
    }
}

// ---------------- P2: bucket rows by active cell-pair (wave-aggregated atomics) ----
__global__ void k_bucket(const float* __restrict__ gates, int* __restrict__ counts,
                         int* __restrict__ rowList) {
    int row = blockIdx.x * 256 + threadIdx.x;
    int lane = threadIdx.x & 63;
    float4 g = *(const float4*)(gates + (size_t)row * 4);
    int i1 = 0; float m1 = g.x;
    if (g.y > m1) { m1 = g.y; i1 = 1; }
    if (g.z > m1) { m1 = g.z; i1 = 2; }
    if (g.w > m1) { m1 = g.w; i1 = 3; }
    int i2 = -1; float m2 = -1.f;
    if (i1 != 0)             { m2 = g.x; i2 = 0; }
    if (i1 != 1 && g.y > m2) { m2 = g.y; i2 = 1; }
    if (i1 != 2 && g.z > m2) { m2 = g.z; i2 = 2; }
    if (i1 != 3 && g.w > m2) { m2 = g.w; i2 = 3; }
    int a = min(i1, i2), b = max(i1, i2);
    int pid = (a == 0) ? (b - 1) : (a == 1) ? (1 + b) : 5;
#pragma unroll
    for (int q = 0; q < 6; ++q) {
        unsigned long long m = __ballot(pid == q);   // uniform execution
        if (pid == q) {
            int leader = __ffsll((long long)m) - 1;
            int base = 0;
            if (lane == leader) base = atomicAdd(counts + q, __popcll(m));
            base = __shfl(base, leader);
            int prefix = __popcll(m & ((1ull << lane) - 1ull));
            rowList[q * 16384 + base + prefix] = row;
        }
    }
}

// ---------------- Main: pair-bucketed GEMM, B-in-register + A-LDS-dbuf ----------
// Structure byte-identical to R15 (best: 61.5 µs) EXCEPT the block decode:
// XCD key swapped to ob (lin&7). Each XCD then reads only its W4 ob-slice
// (~524 KB, L2-resident) -> B register-loads become ~200cy L2 hits fully
// covered by the compute phase, instead of L3 misses that stall the per-tile
// vmcnt(0) barrier. (R11 tested this pre-epilogue-fix and was null; B-path
// is now the top remaining candidate.)
__launch_bounds__(256, 3)
__global__ void k_main(const __hip_bfloat16* __restrict__ featsB,
                       const __hip_bfloat16* __restrict__ W4,
                       const float* __restrict__ cin,
                       const float* __restrict__ gates,
                       const float* __restrict__ bg,
                       const int* __restrict__ counts,
                       const int* __restrict__ rowList,
                       float* __restrict__ out) {
    __shared__ char smem[25600];          // A[2][8192] | cinS 8K | gatesS 1K
    float* oAcc  = (float*)smem;          // [2][64][32] f32 — aliases A bufs only
    float* cinS  = (float*)(smem + 16384);   // [64][32]
    float* gatesS = (float*)(smem + 24576);  // [64][4]

    int tid = threadIdx.x;
    int wave = tid >> 6, lane = tid & 63;
    int wc = wave;                        // (ch, ohh) selector
    int hi = lane >> 4, lsw = lane & 7, l15 = lane & 15;

    // ob-keyed XCD decode: XCD = lin%8 = ob -> per-XCD W4 slice is L2-resident
    int lin = blockIdx.x;                 // [0, 2176)
    int ob = lin & 7;
    int bq = lin >> 3;                    // [0, 272)

    int c0_ = counts[0], c1_ = counts[1], c2_ = counts[2],
        c3_ = counts[3], c4_ = counts[4], c5_ = counts[5];
    int s1 = (c0_ + 63) >> 6;
    int s2 = s1 + ((c1_ + 63) >> 6);
    int s3 = s2 + ((c2_ + 63) >> 6);
    int s4 = s3 + ((c3_ + 63) >> 6);
    int s5 = s4 + ((c4_ + 63) >> 6);
    int total = s5 + ((c5_ + 63) >> 6);
    if (bq >= total) return;
    int p, chunk, cnt, cA, cB;
    if      (bq < s1) { p = 0; chunk = bq;      cnt = c0_; cA = 0; cB = 1; }
    else if (bq < s2) { p = 1; chunk = bq - s1; cnt = c1_; cA = 0; cB = 2; }
    else if (bq < s3) { p = 2; chunk = bq - s2; cnt = c2_; cA = 0; cB = 3; }
    else if (bq < s4) { p = 3; chunk = bq - s3; cnt = c3_; cA = 1; cB = 2; }
    else if (bq < s5) { p = 4; chunk = bq - s4; cnt = c4_; cA = 1; cB = 3; }
    else              { p = 5; chunk = bq - s5; cnt = c5_; cA = 2; cB = 3; }
    int nvalid = min(64, cnt - chunk * 64);
    int rowbase = p * 16384 + chunk * 64;

    int ohh = wc & 1;
    int ch  = wc >> 1;
    int cell = ch ? cB : cA;

    // A gather descriptors (R10-proven): 128-B rows = 8 chunks; swizzle key = row&7
    int e0 = tid,        rA0 = e0 >> 3, gA0 = (e0 & 7) ^ (rA0 & 7);
    int e1 = 256 + tid,  rA1 = e1 >> 3, gA1 = (e1 & 7) ^ (rA1 & 7);
    int grA0 = rowList[rowbase + ((rA0 < nvalid) ? rA0 : 0)];
    int grA1 = rowList[rowbase + ((rA1 < nvalid) ? rA1 : 0)];
    const __hip_bfloat16* sA0 = featsB + (size_t)grA0 * 512 + gA0 * 8;
    const __hip_bfloat16* sA1 = featsB + (size_t)grA1 * 512 + gA1 * 8;
    int dA0 = e0 * 16, dA1 = e1 * 16;

    // B wave base in W4 (R8-proven mapping)
    const __hip_bfloat16* bBw =
        W4 + ((size_t)(cell * 8 + ob) * 128 + ohh * 64) * 512 + lane * 8;

    f32x4 acc[4][4];
#pragma unroll
    for (int m = 0; m < 4; ++m)
#pragma unroll
        for (int n = 0; n < 4; ++n)
            acc[m][n] = (f32x4){0.f, 0.f, 0.f, 0.f};

    short8 br[2][4][2];                   // [buf parity][n][kk] — static after unroll

#define STAGE_A(kt_, buf_) do { \
        GLOAD_LDS16(sA0 + (kt_) * 64, smem + (buf_) * 8192 + dA0); \
        GLOAD_LDS16(sA1 + (kt_) * 64, smem + (buf_) * 8192 + dA1); \
    } while (0)
#define LOAD_B(pb_, kt_) do { \
        _Pragma("unroll") \
        for (int n_ = 0; n_ < 4; ++n_) \
            _Pragma("unroll") \
            for (int kk_ = 0; kk_ < 2; ++kk_) \
                br[pb_][n_][kk_] = *reinterpret_cast<const short8*>( \
                    bBw + n_ * 8192 + ((kt_) * 2 + kk_) * 512); \
    } while (0)

    // prologue: tile 0 + EPILOGUE OPERAND PREFETCH (cin/gates -> LDS)
    STAGE_A(0, 0);
    {
        int ec0 = tid,       rc0 = ec0 >> 3, qc0 = ec0 & 7;
        int ec1 = 256 + tid, rc1 = ec1 >> 3, qc1 = ec1 & 7;
        int gr0 = rowList[rowbase + ((rc0 < nvalid) ? rc0 : 0)];
        int gr1 = rowList[rowbase + ((rc1 < nvalid) ? rc1 : 0)];
        GLOAD_LDS16(cin + (size_t)gr0 * 256 + ob * 32 + qc0 * 4,
                    (char*)cinS + ec0 * 16);
        GLOAD_LDS16(cin + (size_t)gr1 * 256 + ob * 32 + qc1 * 4,
                    (char*)cinS + ec1 * 16);
        if (tid < 64) {
            int gr = rowList[rowbase + ((tid < nvalid) ? tid : 0)];
            GLOAD_LDS16(gates + (size_t)gr * 4, (char*)gatesS + tid * 16);
        }
    }
    LOAD_B(0, 0);
    __syncthreads();                      // drains: A(0), cin, gates in LDS

#pragma unroll
    for (int kt = 0; kt < 8; ++kt) {
        const int buf = kt & 1;
        if (kt < 7) {                     // issue next tile's loads BEFORE compute
            STAGE_A(kt + 1, buf ^ 1);
            LOAD_B(buf ^ 1, kt + 1);
        }
        const char* Ab = smem + buf * 8192;
#pragma unroll
        for (int kk = 0; kk < 2; ++kk) {
            short8 fa[4];
#pragma unroll
            for (int m = 0; m < 4; ++m) {
                int row = m * 16 + l15;
                int chunkc = (kk * 4 + hi) ^ lsw;
                fa[m] = *reinterpret_cast<const short8*>(Ab + row * 128 + chunkc * 16);
            }
#pragma unroll
            for (int m = 0; m < 4; ++m)
#pragma unroll
                for (int n = 0; n < 4; ++n)
                    acc[m][n] = __builtin_amdgcn_mfma_f32_16x16x32_bf16(
                        fa[m], br[buf][n][kk], acc[m][n], 0, 0, 0);
        }
        __syncthreads();  // reads of buf done; vmcnt(0) drain covered by compute
    }
#undef STAGE_A
#undef LOAD_B

    // ---- epilogue: all operands in LDS/registers; fast-approx activations ----
    int og = ob * 32 + ohh * 16 + l15;    // global o in [0,256)
    float bb0 = bg[cell * 1024 + 0 * 256 + og];
    float bb1 = bg[cell * 1024 + 1 * 256 + og];
    float bb2 = bg[cell * 1024 + 2 * 256 + og];
    float bb3 = bg[cell * 1024 + 3 * 256 + og];

#define LSTM_BODY(STORE_OP) \
    _Pragma("unroll") \
    for (int m = 0; m < 4; ++m) { \
        _Pragma("unroll") \
        for (int reg = 0; reg < 4; ++reg) { \
            int r = m * 16 + hi * 4 + reg; \
            float gw = gatesS[r * 4 + cell]; \
            float iv = sigmoidf_(acc[m][0][reg] + bb0); \
            float jv = acc[m][1][reg] + bb1; \
            float fv = sigmoidf_(acc[m][2][reg] + bb2); \
            float ov = sigmoidf_(acc[m][3][reg] + bb3); \
            float cv = cinS[r * 32 + ohh * 16 + l15]; \
            float ncl = fv * cv + iv * tanhf_(jv); \
            float nhl = ov * tanhf_(ncl); \
            oAcc[r * 32 + ohh * 16 + l15] STORE_OP gw * nhl; \
            oAcc[2048 + r * 32 + ohh * 16 + l15] STORE_OP gw * ncl; \
        } \
    }

    if (ch == 0) { LSTM_BODY(=) }     // cell-A waves cover all [2][64][32] slots
    __syncthreads();
    if (ch == 1) { LSTM_BODY(+=) }    // cell-B waves accumulate
    __syncthreads();
#undef LSTM_BODY

    {
        int r = tid >> 2, q = tid & 3;
        if (r < nvalid) {
            int grow = rowList[rowbase + r];
            size_t obase = (size_t)grow * 256 + ob * 32 + q * 8;
            *(float4*)&out[obase]     = *(float4*)&oAcc[r * 32 + q * 8];
            *(float4*)&out[obase + 4] = *(float4*)&oAcc[r * 32 + q * 8 + 4];
            *(float4*)&out[(size_t)NB * 256 + obase]     = *(float4*)&oAcc[2048 + r * 32 + q * 8];
            *(float4*)&out[(size_t)NB * 256 + obase + 4] = *(float4*)&oAcc[2048 + r * 32 + q * 8 + 4];
        }
    }
}

extern "C" void kernel_launch(void* const* d_in, const int* in_sizes, int n_in,
                              void* d_out, int out_size, void* d_ws, size_t ws_size,
                              hipStream_t stream) {
    const float* x  = (const float*)d_in[0];
    const float* c  = (const float*)d_in[1];
    const float* h  = (const float*)d_in[2];
    const float* Wg = (const float*)d_in[3];
    const float* bg = (const float*)d_in[4];
    const float* Wc = (const float*)d_in[5];
    const float* bc = (const float*)d_in[6];
    float* out = (float*)d_out;

    const size_t featsB_bytes = (size_t)NB * DD * 2;        // 16.78 MB
    const size_t w4_bytes     = (size_t)NCOLS * DD * 2;     // 4.19 MB
    const size_t gates_bytes  = (size_t)NB * 4 * 4;         // 0.26 MB
    const size_t counts_bytes = 256;
    const size_t rlist_bytes  = (size_t)6 * 16384 * 4;      // 0.39 MB
    if (ws_size < featsB_bytes + w4_bytes + gates_bytes + counts_bytes + rlist_bytes)
        return;

    char* ws = (char*)d_ws;
    __hip_bfloat16* featsB = (__hip_bfloat16*)ws;
    __hip_bfloat16* W4     = (__hip_bfloat16*)(ws + featsB_bytes);
    float*          gatesW = (float*)(ws + featsB_bytes + w4_bytes);
    int*            counts = (int*)(ws + featsB_bytes + w4_bytes + gates_bytes);
    int*            rowLst = (int*)(ws + featsB_bytes + w4_bytes + gates_bytes + counts_bytes);

    hipMemsetAsync(counts, 0, 32, stream);
    k_pre<<<dim3(5120), dim3(256), 0, stream>>>(x, h, Wc, bc, Wg, featsB, gatesW, W4);
    k_bucket<<<dim3(64), dim3(256), 0, stream>>>(gatesW, counts, rowLst);
    // 2176 = 272 bq x 8 obs; lin = bq*8 + ob so XCD == ob; excess bq exit early
    k_main<<<dim3(2176), dim3(256), 0, stream>>>(featsB, W4, c, gatesW, bg,
                                                 counts, rowLst, out);
}

// Round 19
// 83.003 us; speedup vs baseline: 1.2979x; 1.2563x over previous
//
#include <hip/hip_runtime.h>
#include <hip/hip_bf16.h>

// Problem constants
#define NB 16384      // batch rows
#define DD 512        // IN+OUT
#define NCOLS 4096    // 4*OUT*NCELL

typedef __attribute__((ext_vector_type(8))) short short8;
typedef __attribute__((ext_vector_type(4))) float f32x4;

// Fast-approx activations (R15-proven: output tol 0.0837 >> 1-ulp rcp/exp2 err)
__device__ __forceinline__ float sigmoidf_(float x) {
    float e = __builtin_amdgcn_exp2f(-1.442695041f * x);   // exp(-x)
    return __builtin_amdgcn_rcpf(1.f + e);
}
__device__ __forceinline__ float tanhf_(float x) {
    float e = __builtin_amdgcn_exp2f(-2.885390082f * x);   // exp(-2x)
    return 2.f * __builtin_amdgcn_rcpf(1.f + e) - 1.f;
}

#define GLOAD_LDS16(g, l) __builtin_amdgcn_global_load_lds( \
    (__attribute__((address_space(1))) void*)(g), \
    (__attribute__((address_space(3))) void*)(l), 16, 0, 0)

// ---------------- P1 (fused): feats->bf16 + ctrl gates | W_gates repack to W4 ----
// Also zeroes counts (block 0) — removes the memset dispatch node.
__global__ void k_pre(const float* __restrict__ x, const float* __restrict__ h,
                      const float* __restrict__ Wc, const float* __restrict__ bc,
                      const float* __restrict__ Wg,
                      __hip_bfloat16* __restrict__ featsB, float* __restrict__ gates,
                      __hip_bfloat16* __restrict__ W4, int* __restrict__ counts) {
    int bid = blockIdx.x;
    if (bid == 0 && threadIdx.x < 6) counts[threadIdx.x] = 0;
    if (bid < 4096) {
        int wave = bid * 4 + (threadIdx.x >> 6);  // == row
        int lane = threadIdx.x & 63;
        int row = wave;
        int k0 = lane * 8;
        const float* src = (k0 < 256) ? (x + (size_t)row * 256 + k0)
                                      : (h + (size_t)row * 256 + k0 - 256);
        float4 f0 = ((const float4*)src)[0];
        float4 f1 = ((const float4*)src)[1];
        float fv[8] = {f0.x, f0.y, f0.z, f0.w, f1.x, f1.y, f1.z, f1.w};
        __hip_bfloat16 tmp[8];
#pragma unroll
        for (int j = 0; j < 8; ++j) tmp[j] = __float2bfloat16(fv[j]);
        *reinterpret_cast<short8*>(featsB + (size_t)row * 512 + k0) =
            *reinterpret_cast<short8*>(tmp);
        float acc[4] = {0.f, 0.f, 0.f, 0.f};
#pragma unroll
        for (int j = 0; j < 8; ++j) {
            float4 w = ((const float4*)Wc)[k0 + j];
            acc[0] += fv[j] * w.x; acc[1] += fv[j] * w.y;
            acc[2] += fv[j] * w.z; acc[3] += fv[j] * w.w;
        }
#pragma unroll
        for (int off = 32; off; off >>= 1) {
#pragma unroll
            for (int c = 0; c < 4; ++c) acc[c] += __shfl_xor(acc[c], off);
        }
        if (lane == 0) {
            float l[4];
#pragma unroll
            for (int c = 0; c < 4; ++c) l[c] = acc[c] + bc[c];
            int i1 = 0;
#pragma unroll
            for (int c = 1; c < 4; ++c) if (l[c] > l[i1]) i1 = c;  // ties -> lowest
            int i2 = -1;
#pragma unroll
            for (int c = 0; c < 4; ++c)
                if (c != i1 && (i2 < 0 || l[c] > l[i2])) i2 = c;
            // selection must match numpy: f32 logits, exact expf here (cheap, once)
            float e = __expf(l[i2] - l[i1]);   // <= 1
            float p1 = 1.f / (1.f + e);
            float p2 = e / (1.f + e);
            float g[4] = {0.f, 0.f, 0.f, 0.f};
            g[i1] = p1; g[i2] = p2;
            float4 gv; gv.x = g[0]; gv.y = g[1]; gv.z = g[2]; gv.w = g[3];
            *(float4*)(gates + (size_t)row * 4) = gv;
        }
    } else {
        int c = (bid - 4096) * 256 + threadIdx.x;   // chunk id, 0..262143
        int lane = c & 63;
        int kkg  = (c >> 6) & 15;
        int rowg = (c >> 10) & 7;
        int ob   = (c >> 13) & 7;
        int cell = c >> 16;
        int oi = lane & 15, hi = lane >> 4;
        int gate = rowg & 3, oh = rowg >> 2;
        int col = cell * 1024 + gate * 256 + ob * 32 + oh * 16 + oi;
        int kb = kkg * 32 + hi * 8;
        __hip_bfloat16 tmp[8];
#pragma unroll
        for (int j = 0; j < 8; ++j)
            tmp[j] = __float2bfloat16(Wg[(size_t)(kb + j) * 4096 + col]);
        *reinterpret_cast<short8*>(W4 + (size_t)c * 8) = *reinterpret_cast<short8*>(tmp);
    }
}

// ---------------- P2: bucket rows, TWO-LEVEL aggregation (<=384 atomics) ---------
// Wave-level ballot -> per-block LDS reduce -> one atomicAdd per block per
// non-empty pid (vs R5's 1536 wave-level atomics on 6 hot words).
__global__ void k_bucket(const float* __restrict__ gates, int* __restrict__ counts,
                         int* __restrict__ rowList) {
    __shared__ int wcnt[4][6];
    __shared__ int wbase[4][6];
    int tid = threadIdx.x;
    int wave = tid >> 6, lane = tid & 63;
    int row = blockIdx.x * 256 + tid;
    float4 g = *(const float4*)(gates + (size_t)row * 4);
    int i1 = 0; float m1 = g.x;
    if (g.y > m1) { m1 = g.y; i1 = 1; }
    if (g.z > m1) { m1 = g.z; i1 = 2; }
    if (g.w > m1) { m1 = g.w; i1 = 3; }
    int i2 = -1; float m2 = -1.f;
    if (i1 != 0)             { m2 = g.x; i2 = 0; }
    if (i1 != 1 && g.y > m2) { m2 = g.y; i2 = 1; }
    if (i1 != 2 && g.z > m2) { m2 = g.z; i2 = 2; }
    if (i1 != 3 && g.w > m2) { m2 = g.w; i2 = 3; }
    int a = min(i1, i2), b = max(i1, i2);
    int pid = (a == 0) ? (b - 1) : (a == 1) ? (1 + b) : 5;
    int pre = 0;
#pragma unroll
    for (int q = 0; q < 6; ++q) {
        unsigned long long m = __ballot(pid == q);   // uniform execution
        if (pid == q) pre = __popcll(m & ((1ull << lane) - 1ull));
        if (lane == 0) wcnt[wave][q] = __popcll(m);
    }
    __syncthreads();
    if (tid < 6) {
        int q = tid;
        int t0 = wcnt[0][q], t1 = wcnt[1][q], t2 = wcnt[2][q], t3 = wcnt[3][q];
        int tot = t0 + t1 + t2 + t3;
        int base = (tot > 0) ? atomicAdd(counts + q, tot) : 0;
        wbase[0][q] = base;
        wbase[1][q] = base + t0;
        wbase[2][q] = base + t0 + t1;
        wbase[3][q] = base + t0 + t1 + t2;
    }
    __syncthreads();
    rowList[pid * 16384 + wbase[wave][pid] + pre] = row;
}

// ---------------- Main: pair-bucketed GEMM, B-in-register + A-LDS-dbuf ----------
// R15 verbatim (best: 61.5 µs k_main): bq%8 XCD decode, B wave-private in
// registers from W4 (1KB coalesced wave loads), A via global_load_lds dbuf,
// ONE __syncthreads per tile, epilogue operands prefetched to LDS (R14),
// fast-approx activations (R15).
__launch_bounds__(256, 3)
__global__ void k_main(const __hip_bfloat16* __restrict__ featsB,
                       const __hip_bfloat16* __restrict__ W4,
                       const float* __restrict__ cin,
                       const float* __restrict__ gates,
                       const float* __restrict__ bg,
                       const int* __restrict__ counts,
                       const int* __restrict__ rowList,
                       float* __restrict__ out) {
    __shared__ char smem[25600];          // A[2][8192] | cinS 8K | gatesS 1K
    float* oAcc  = (float*)smem;          // [2][64][32] f32 — aliases A bufs only
    float* cinS  = (float*)(smem + 16384);   // [64][32]
    float* gatesS = (float*)(smem + 24576);  // [64][4]

    int tid = threadIdx.x;
    int wave = tid >> 6, lane = tid & 63;
    int wc = wave;                        // (ch, ohh) selector
    int hi = lane >> 4, lsw = lane & 7, l15 = lane & 15;

    // R10/R15 XCD-clustered decode: lin%8 = XCD = bq%8
    int lin = blockIdx.x;                 // [0, 2176)
    int r_ = lin & 7;
    int v_ = lin >> 3;                    // [0, 272)
    int ob = v_ & 7;
    int bq = r_ + ((v_ >> 3) << 3);       // [0, 272), bq%8 == r_

    int c0_ = counts[0], c1_ = counts[1], c2_ = counts[2],
        c3_ = counts[3], c4_ = counts[4], c5_ = counts[5];
    int s1 = (c0_ + 63) >> 6;
    int s2 = s1 + ((c1_ + 63) >> 6);
    int s3 = s2 + ((c2_ + 63) >> 6);
    int s4 = s3 + ((c3_ + 63) >> 6);
    int s5 = s4 + ((c4_ + 63) >> 6);
    int total = s5 + ((c5_ + 63) >> 6);
    if (bq >= total) return;
    int p, chunk, cnt, cA, cB;
    if      (bq < s1) { p = 0; chunk = bq;      cnt = c0_; cA = 0; cB = 1; }
    else if (bq < s2) { p = 1; chunk = bq - s1; cnt = c1_; cA = 0; cB = 2; }
    else if (bq < s3) { p = 2; chunk = bq - s2; cnt = c2_; cA = 0; cB = 3; }
    else if (bq < s4) { p = 3; chunk = bq - s3; cnt = c3_; cA = 1; cB = 2; }
    else if (bq < s5) { p = 4; chunk = bq - s4; cnt = c4_; cA = 1; cB = 3; }
    else              { p = 5; chunk = bq - s5; cnt = c5_; cA = 2; cB = 3; }
    int nvalid = min(64, cnt - chunk * 64);
    int rowbase = p * 16384 + chunk * 64;

    int ohh = wc & 1;
    int ch  = wc >> 1;
    int cell = ch ? cB : cA;

    // A gather descriptors (R10-proven): 128-B rows = 8 chunks; swizzle key = row&7
    int e0 = tid,        rA0 = e0 >> 3, gA0 = (e0 & 7) ^ (rA0 & 7);
    int e1 = 256 + tid,  rA1 = e1 >> 3, gA1 = (e1 & 7) ^ (rA1 & 7);
    int grA0 = rowList[rowbase + ((rA0 < nvalid) ? rA0 : 0)];
    int grA1 = rowList[rowbase + ((rA1 < nvalid) ? rA1 : 0)];
    const __hip_bfloat16* sA0 = featsB + (size_t)grA0 * 512 + gA0 * 8;
    const __hip_bfloat16* sA1 = featsB + (size_t)grA1 * 512 + gA1 * 8;
    int dA0 = e0 * 16, dA1 = e1 * 16;

    // B wave base in W4 (R8-proven mapping)
    const __hip_bfloat16* bBw =
        W4 + ((size_t)(cell * 8 + ob) * 128 + ohh * 64) * 512 + lane * 8;

    f32x4 acc[4][4];
#pragma unroll
    for (int m = 0; m < 4; ++m)
#pragma unroll
        for (int n = 0; n < 4; ++n)
            acc[m][n] = (f32x4){0.f, 0.f, 0.f, 0.f};

    short8 br[2][4][2];                   // [buf parity][n][kk] — static after unroll

#define STAGE_A(kt_, buf_) do { \
        GLOAD_LDS16(sA0 + (kt_) * 64, smem + (buf_) * 8192 + dA0); \
        GLOAD_LDS16(sA1 + (kt_) * 64, smem + (buf_) * 8192 + dA1); \
    } while (0)
#define LOAD_B(pb_, kt_) do { \
        _Pragma("unroll") \
        for (int n_ = 0; n_ < 4; ++n_) \
            _Pragma("unroll") \
            for (int kk_ = 0; kk_ < 2; ++kk_) \
                br[pb_][n_][kk_] = *reinterpret_cast<const short8*>( \
                    bBw + n_ * 8192 + ((kt_) * 2 + kk_) * 512); \
    } while (0)

    // prologue: tile 0 + EPILOGUE OPERAND PREFETCH (cin/gates -> LDS)
    STAGE_A(0, 0);
    {
        int ec0 = tid,       rc0 = ec0 >> 3, qc0 = ec0 & 7;
        int ec1 = 256 + tid, rc1 = ec1 >> 3, qc1 = ec1 & 7;
        int gr0 = rowList[rowbase + ((rc0 < nvalid) ? rc0 : 0)];
        int gr1 = rowList[rowbase + ((rc1 < nvalid) ? rc1 : 0)];
        GLOAD_LDS16(cin + (size_t)gr0 * 256 + ob * 32 + qc0 * 4,
                    (char*)cinS + ec0 * 16);
        GLOAD_LDS16(cin + (size_t)gr1 * 256 + ob * 32 + qc1 * 4,
                    (char*)cinS + ec1 * 16);
        if (tid < 64) {
            int gr = rowList[rowbase + ((tid < nvalid) ? tid : 0)];
            GLOAD_LDS16(gates + (size_t)gr * 4, (char*)gatesS + tid * 16);
        }
    }
    LOAD_B(0, 0);
    __syncthreads();                      // drains: A(0), cin, gates in LDS

#pragma unroll
    for (int kt = 0; kt < 8; ++kt) {
        const int buf = kt & 1;
        if (kt < 7) {                     // issue next tile's loads BEFORE compute
            STAGE_A(kt + 1, buf ^ 1);
            LOAD_B(buf ^ 1, kt + 1);
        }
        const char* Ab = smem + buf * 8192;
#pragma unroll
        for (int kk = 0; kk < 2; ++kk) {
            short8 fa[4];
#pragma unroll
            for (int m = 0; m < 4; ++m) {
                int row = m * 16 + l15;
                int chunkc = (kk * 4 + hi) ^ lsw;
                fa[m] = *reinterpret_cast<const short8*>(Ab + row * 128 + chunkc * 16);
            }
#pragma unroll
            for (int m = 0; m < 4; ++m)
#pragma unroll
                for (int n = 0; n < 4; ++n)
                    acc[m][n] = __builtin_amdgcn_mfma_f32_16x16x32_bf16(
                        fa[m], br[buf][n][kk], acc[m][n], 0, 0, 0);
        }
        __syncthreads();  // reads of buf done; vmcnt(0) drain covered by compute
    }
#undef STAGE_A
#undef LOAD_B

    // ---- epilogue: all operands in LDS/registers; fast-approx activations ----
    int og = ob * 32 + ohh * 16 + l15;    // global o in [0,256)
    float bb0 = bg[cell * 1024 + 0 * 256 + og];
    float bb1 = bg[cell * 1024 + 1 * 256 + og];
    float bb2 = bg[cell * 1024 + 2 * 256 + og];
    float bb3 = bg[cell * 1024 + 3 * 256 + og];

#define LSTM_BODY(STORE_OP) \
    _Pragma("unroll") \
    for (int m = 0; m < 4; ++m) { \
        _Pragma("unroll") \
        for (int reg = 0; reg < 4; ++reg) { \
            int r = m * 16 + hi * 4 + reg; \
            float gw = gatesS[r * 4 + cell]; \
            float iv = sigmoidf_(acc[m][0][reg] + bb0); \
            float jv = acc[m][1][reg] + bb1; \
            float fv = sigmoidf_(acc[m][2][reg] + bb2); \
            float ov = sigmoidf_(acc[m][3][reg] + bb3); \
            float cv = cinS[r * 32 + ohh * 16 + l15]; \
            float ncl = fv * cv + iv * tanhf_(jv); \
            float nhl = ov * tanhf_(ncl); \
            oAcc[r * 32 + ohh * 16 + l15] STORE_OP gw * nhl; \
            oAcc[2048 + r * 32 + ohh * 16 + l15] STORE_OP gw * ncl; \
        } \
    }

    if (ch == 0) { LSTM_BODY(=) }     // cell-A waves cover all [2][64][32] slots
    __syncthreads();
    if (ch == 1) { LSTM_BODY(+=) }    // cell-B waves accumulate
    __syncthreads();
#undef LSTM_BODY

    {
        int r = tid >> 2, q = tid & 3;
        if (r < nvalid) {
            int grow = rowList[rowbase + r];
            size_t obase = (size_t)grow * 256 + ob * 32 + q * 8;
            *(float4*)&out[obase]     = *(float4*)&oAcc[r * 32 + q * 8];
            *(float4*)&out[obase + 4] = *(float4*)&oAcc[r * 32 + q * 8 + 4];
            *(float4*)&out[(size_t)NB * 256 + obase]     = *(float4*)&oAcc[2048 + r * 32 + q * 8];
            *(float4*)&out[(size_t)NB * 256 + obase + 4] = *(float4*)&oAcc[2048 + r * 32 + q * 8 + 4];
        }
    }
}

extern "C" void kernel_launch(void* const* d_in, const int* in_sizes, int n_in,
                              void* d_out, int out_size, void* d_ws, size_t ws_size,
                              hipStream_t stream) {
    const float* x  = (const float*)d_in[0];
    const float* c  = (const float*)d_in[1];
    const float* h  = (const float*)d_in[2];
    const float* Wg = (const float*)d_in[3];
    const float* bg = (const float*)d_in[4];
    const float* Wc = (const float*)d_in[5];
    const float* bc = (const float*)d_in[6];
    float* out = (float*)d_out;

    const size_t featsB_bytes = (size_t)NB * DD * 2;        // 16.78 MB
    const size_t w4_bytes     = (size_t)NCOLS * DD * 2;     // 4.19 MB
    const size_t gates_bytes  = (size_t)NB * 4 * 4;         // 0.26 MB
    const size_t counts_bytes = 256;
    const size_t rlist_bytes  = (size_t)6 * 16384 * 4;      // 0.39 MB
    if (ws_size < featsB_bytes + w4_bytes + gates_bytes + counts_bytes + rlist_bytes)
        return;

    char* ws = (char*)d_ws;
    __hip_bfloat16* featsB = (__hip_bfloat16*)ws;
    __hip_bfloat16* W4     = (__hip_bfloat16*)(ws + featsB_bytes);
    float*          gatesW = (float*)(ws + featsB_bytes + w4_bytes);
    int*            counts = (int*)(ws + featsB_bytes + w4_bytes + gates_bytes);
    int*            rowLst = (int*)(ws + featsB_bytes + w4_bytes + gates_bytes + counts_bytes);

    k_pre<<<dim3(5120), dim3(256), 0, stream>>>(x, h, Wc, bc, Wg, featsB, gatesW,
                                                W4, counts);
    k_bucket<<<dim3(64), dim3(256), 0, stream>>>(gatesW, counts, rowLst);
    // 2176 = 8 XCD-residues x 34 chunk-groups x 8 obs; blocks with bq>=total exit
    k_main<<<dim3(2176), dim3(256), 0, stream>>>(featsB, W4, c, gatesW, bg,
                                                 counts, rowLst, out);
}